// Round 1
// baseline (601.750 us; speedup 1.0000x reference)
//
#include <hip/hip_runtime.h>

#define N_PTS 1048576
#define B_SEG 4096
#define C_IN  96
#define LN_EPS 1e-5f

__device__ __forceinline__ int lower_bound_i(const int* __restrict__ a, int n, int v){
  int lo = 0, hi = n;
  while(lo < hi){
    int m = (lo + hi) >> 1;
    if(a[m] < v) lo = m + 1; else hi = m;
  }
  return lo;
}

__device__ __forceinline__ float f4e(const float4& v, int j){
  return j==0 ? v.x : j==1 ? v.y : j==2 ? v.z : v.w;
}

// ---------------- Kernel 1: segment mean pooling ----------------
// grid = 4096 (one block per segment), block = 192 (8 rows x 24 float4 groups)
__global__ __launch_bounds__(192) void pool_kernel(
    const float* __restrict__ feat, const int* __restrict__ seg,
    float* __restrict__ pooled)
{
  const int b   = blockIdx.x;
  const int tid = threadIdx.x;
  const int lo  = lower_bound_i(seg, N_PTS, b);
  const int hi  = lower_bound_i(seg, N_PTS, b + 1);
  const int g = tid % 24;      // float4 group within row (24*4 = 96 channels)
  const int r = tid / 24;      // 0..7 row phase
  const float4* __restrict__ f4 = (const float4*)feat;
  float ax = 0.f, ay = 0.f, az = 0.f, aw = 0.f;
  for(int row = lo + r; row < hi; row += 8){
    float4 v = f4[(size_t)row * 24 + g];
    ax += v.x; ay += v.y; az += v.z; aw += v.w;
  }
  __shared__ float4 part[192];
  part[tid] = make_float4(ax, ay, az, aw);
  __syncthreads();
  if(tid < 24){
    float sx=0.f, sy=0.f, sz=0.f, sw=0.f;
    #pragma unroll
    for(int rr=0; rr<8; rr++){
      float4 v = part[rr*24 + tid];
      sx += v.x; sy += v.y; sz += v.z; sw += v.w;
    }
    int cnt = hi - lo; if(cnt < 1) cnt = 1;
    float inv = 1.f / (float)cnt;
    ((float4*)pooled)[b*24 + tid] = make_float4(sx*inv, sy*inv, sz*inv, sw*inv);
  }
}

// ---------------- Kernel 2: fused MLP heads ----------------
// grid = 512 blocks, 256 threads, 8 samples per block.
__global__ __launch_bounds__(256) void mlp_kernel(
    const float* __restrict__ pooled, const int* __restrict__ class_ids,
    const float* __restrict__ cW1, const float* __restrict__ cb1,
    const float* __restrict__ cg1, const float* __restrict__ cbe1,
    const float* __restrict__ cW2, const float* __restrict__ cb2,
    const float* __restrict__ cg2, const float* __restrict__ cbe2,
    const float* __restrict__ cW3, const float* __restrict__ cb3,
    const float* __restrict__ rW1, const float* __restrict__ rb1,
    const float* __restrict__ rg1, const float* __restrict__ rbe1,
    const float* __restrict__ rW2, const float* __restrict__ rb2,
    const float* __restrict__ rg2, const float* __restrict__ rbe2,
    const float* __restrict__ rW3, const float* __restrict__ rb3,
    float* __restrict__ out)
{
  const int tid = threadIdx.x;
  const int blk = blockIdx.x;
  const int b0  = blk * 8;
  const int lane = tid & 63;
  const int wv   = tid >> 6;

  __shared__ float p   [8*96];
  __shared__ float h1  [8*256];
  __shared__ float h2  [8*132];   // padded stride 132 -> conflict-free column reads in c3
  __shared__ float r1b [8*128];
  __shared__ float r2b [8*68];    // padded stride 68
  __shared__ float couts[24];
  __shared__ int   kcls[8];
  __shared__ float redbuf[4][32];
  __shared__ float stats[32];

  for(int i = tid; i < 8*96; i += 256) p[i] = pooled[b0*96 + i];
  if(tid < 8) kcls[tid] = class_ids[b0 + tid];
  __syncthreads();

  //======== coarse L1: 96 -> 256, LN, ReLU ========
  {
    const int o = tid;                 // output channel
    float acc[8];
    float bias = cb1[o];
    #pragma unroll
    for(int s=0;s<8;s++) acc[s] = bias;
    for(int c0=0;c0<96;c0+=4){
      float4 pv[8];
      #pragma unroll
      for(int s=0;s<8;s++) pv[s] = *(const float4*)&p[s*96 + c0];
      #pragma unroll
      for(int j=0;j<4;j++){
        float w = cW1[(c0+j)*256 + o];
        #pragma unroll
        for(int s=0;s<8;s++) acc[s] = fmaf(f4e(pv[s], j), w, acc[s]);
      }
    }
    float sum[8], sq[8];
    #pragma unroll
    for(int s=0;s<8;s++){ sum[s]=acc[s]; sq[s]=acc[s]*acc[s]; }
    #pragma unroll
    for(int m=32;m>=1;m>>=1){
      #pragma unroll
      for(int s=0;s<8;s++){
        sum[s] += __shfl_xor(sum[s], m, 64);
        sq[s]  += __shfl_xor(sq[s],  m, 64);
      }
    }
    if(lane == 0){
      #pragma unroll
      for(int s=0;s<8;s++){ redbuf[wv][s]=sum[s]; redbuf[wv][8+s]=sq[s]; }
    }
    __syncthreads();
    if(tid < 16) stats[tid] = redbuf[0][tid]+redbuf[1][tid]+redbuf[2][tid]+redbuf[3][tid];
    __syncthreads();
    float gg = cg1[o], be = cbe1[o];
    #pragma unroll
    for(int s=0;s<8;s++){
      float mean = stats[s]   * (1.f/256.f);
      float var  = stats[8+s] * (1.f/256.f) - mean*mean;
      float rstd = rsqrtf(var + LN_EPS);
      float v = (acc[s]-mean)*rstd*gg + be;
      h1[s*256 + o] = v > 0.f ? v : 0.f;
    }
    __syncthreads();
  }

  //======== coarse L2: 256 -> 128, LN, ReLU ========
  {
    const int o = tid & 127;
    const int g = tid >> 7;            // 0..1 : samples g*4 .. g*4+3
    float acc[4];
    float bias = cb2[o];
    #pragma unroll
    for(int s=0;s<4;s++) acc[s] = bias;
    for(int c0=0;c0<256;c0+=4){
      float4 hv[4];
      #pragma unroll
      for(int s=0;s<4;s++) hv[s] = *(const float4*)&h1[(g*4+s)*256 + c0];
      #pragma unroll
      for(int j=0;j<4;j++){
        float w = cW2[(c0+j)*128 + o];
        #pragma unroll
        for(int s=0;s<4;s++) acc[s] = fmaf(f4e(hv[s], j), w, acc[s]);
      }
    }
    float sum[4], sq[4];
    #pragma unroll
    for(int s=0;s<4;s++){ sum[s]=acc[s]; sq[s]=acc[s]*acc[s]; }
    #pragma unroll
    for(int m=32;m>=1;m>>=1){
      #pragma unroll
      for(int s=0;s<4;s++){
        sum[s] += __shfl_xor(sum[s], m, 64);
        sq[s]  += __shfl_xor(sq[s],  m, 64);
      }
    }
    if(lane == 0){
      #pragma unroll
      for(int s=0;s<4;s++){ redbuf[wv][s]=sum[s]; redbuf[wv][4+s]=sq[s]; }
    }
    __syncthreads();
    if(tid < 16){ int gq = tid>>3, i = tid&7; stats[tid] = redbuf[2*gq][i] + redbuf[2*gq+1][i]; }
    __syncthreads();
    float gg = cg2[o], be = cbe2[o];
    #pragma unroll
    for(int s=0;s<4;s++){
      float mean = stats[g*8+s]   * (1.f/128.f);
      float var  = stats[g*8+4+s] * (1.f/128.f) - mean*mean;
      float rstd = rsqrtf(var + LN_EPS);
      float v = (acc[s]-mean)*rstd*gg + be;
      h2[(g*4+s)*132 + o] = v > 0.f ? v : 0.f;
    }
    __syncthreads();
  }

  //======== coarse L3: 128 -> 3 (no sync inside) ========
  if(tid < 24){
    int s = tid/3, j = tid - 3*(tid/3);
    float a = cb3[j];
    for(int c=0;c<128;c++) a = fmaf(h2[s*132 + c], cW3[c*3 + j], a);
    couts[tid] = a;
  }

  //======== refine L1 (routed): 96 -> 128, LN, ReLU ========
  {
    const int o = tid & 127;
    const int g = tid >> 7;
    int ks[4]; const float* wp[4]; float acc[4];
    #pragma unroll
    for(int s=0;s<4;s++){
      ks[s]  = kcls[g*4+s];
      wp[s]  = rW1 + ks[s]*(96*128) + o;
      acc[s] = rb1[ks[s]*128 + o];
    }
    for(int c0=0;c0<96;c0+=4){
      float4 pv[4];
      #pragma unroll
      for(int s=0;s<4;s++) pv[s] = *(const float4*)&p[(g*4+s)*96 + c0];
      #pragma unroll
      for(int j=0;j<4;j++){
        #pragma unroll
        for(int s=0;s<4;s++){
          float w = wp[s][(c0+j)*128];
          acc[s] = fmaf(f4e(pv[s], j), w, acc[s]);
        }
      }
    }
    float sum[4], sq[4];
    #pragma unroll
    for(int s=0;s<4;s++){ sum[s]=acc[s]; sq[s]=acc[s]*acc[s]; }
    #pragma unroll
    for(int m=32;m>=1;m>>=1){
      #pragma unroll
      for(int s=0;s<4;s++){
        sum[s] += __shfl_xor(sum[s], m, 64);
        sq[s]  += __shfl_xor(sq[s],  m, 64);
      }
    }
    if(lane == 0){
      #pragma unroll
      for(int s=0;s<4;s++){ redbuf[wv][s]=sum[s]; redbuf[wv][4+s]=sq[s]; }
    }
    __syncthreads();
    if(tid < 16){ int gq = tid>>3, i = tid&7; stats[tid] = redbuf[2*gq][i] + redbuf[2*gq+1][i]; }
    __syncthreads();
    #pragma unroll
    for(int s=0;s<4;s++){
      float mean = stats[g*8+s]   * (1.f/128.f);
      float var  = stats[g*8+4+s] * (1.f/128.f) - mean*mean;
      float rstd = rsqrtf(var + LN_EPS);
      float v = (acc[s]-mean)*rstd*rg1[ks[s]*128+o] + rbe1[ks[s]*128+o];
      r1b[(g*4+s)*128 + o] = v > 0.f ? v : 0.f;
    }
    __syncthreads();
  }

  //======== refine L2 (routed): 128 -> 64, LN, ReLU ========
  {
    const int o = tid & 63;
    const int g = tid >> 6;            // 0..3 : samples g*2, g*2+1
    int ks[2]; const float* wp[2]; float acc[2];
    #pragma unroll
    for(int s=0;s<2;s++){
      ks[s]  = kcls[g*2+s];
      wp[s]  = rW2 + ks[s]*(128*64) + o;
      acc[s] = rb2[ks[s]*64 + o];
    }
    for(int c0=0;c0<128;c0+=4){
      float4 rv[2];
      #pragma unroll
      for(int s=0;s<2;s++) rv[s] = *(const float4*)&r1b[(g*2+s)*128 + c0];
      #pragma unroll
      for(int j=0;j<4;j++){
        #pragma unroll
        for(int s=0;s<2;s++){
          float w = wp[s][(c0+j)*64];
          acc[s] = fmaf(f4e(rv[s], j), w, acc[s]);
        }
      }
    }
    float sum[2], sq[2];
    #pragma unroll
    for(int s=0;s<2;s++){ sum[s]=acc[s]; sq[s]=acc[s]*acc[s]; }
    #pragma unroll
    for(int m=32;m>=1;m>>=1){
      #pragma unroll
      for(int s=0;s<2;s++){
        sum[s] += __shfl_xor(sum[s], m, 64);
        sq[s]  += __shfl_xor(sq[s],  m, 64);
      }
    }
    // group == one full wave: every lane already has the totals
    #pragma unroll
    for(int s=0;s<2;s++){
      float mean = sum[s] * (1.f/64.f);
      float var  = sq[s]  * (1.f/64.f) - mean*mean;
      float rstd = rsqrtf(var + LN_EPS);
      float v = (acc[s]-mean)*rstd*rg2[ks[s]*64+o] + rbe2[ks[s]*64+o];
      r2b[(g*2+s)*68 + o] = v > 0.f ? v : 0.f;
    }
    __syncthreads();
  }

  //======== refine L3 + combine ========
  if(tid < 24){
    int s = tid/3, j = tid - 3*(tid/3);
    int k = kcls[s];
    float a = rb3[k*3 + j];
    const float* w = rW3 + k*192 + j;
    for(int c=0;c<64;c++) a = fmaf(r2b[s*68 + c], w[c*3], a);
    out[(b0+s)*3 + j] = a + couts[tid];
  }
}

extern "C" void kernel_launch(void* const* d_in, const int* in_sizes, int n_in,
                              void* d_out, int out_size, void* d_ws, size_t ws_size,
                              hipStream_t stream)
{
  const float* feat = (const float*)d_in[0];
  const int*   seg  = (const int*)d_in[1];
  const int*   cls  = (const int*)d_in[2];
  const float* cW1  = (const float*)d_in[3];
  const float* cb1  = (const float*)d_in[4];
  const float* cg1  = (const float*)d_in[5];
  const float* cbe1 = (const float*)d_in[6];
  const float* cW2  = (const float*)d_in[7];
  const float* cb2  = (const float*)d_in[8];
  const float* cg2  = (const float*)d_in[9];
  const float* cbe2 = (const float*)d_in[10];
  const float* cW3  = (const float*)d_in[11];
  const float* cb3  = (const float*)d_in[12];
  const float* rW1  = (const float*)d_in[13];
  const float* rb1  = (const float*)d_in[14];
  const float* rg1  = (const float*)d_in[15];
  const float* rbe1 = (const float*)d_in[16];
  const float* rW2  = (const float*)d_in[17];
  const float* rb2  = (const float*)d_in[18];
  const float* rg2  = (const float*)d_in[19];
  const float* rbe2 = (const float*)d_in[20];
  const float* rW3  = (const float*)d_in[21];
  const float* rb3  = (const float*)d_in[22];
  float* out    = (float*)d_out;
  float* pooled = (float*)d_ws;   // 4096*96 floats = 1.57 MB scratch

  pool_kernel<<<B_SEG, 192, 0, stream>>>(feat, seg, pooled);
  mlp_kernel<<<B_SEG/8, 256, 0, stream>>>(pooled, cls,
      cW1, cb1, cg1, cbe1, cW2, cb2, cg2, cbe2, cW3, cb3,
      rW1, rb1, rg1, rbe1, rW2, rb2, rg2, rbe2, rW3, rb3, out);
}